// Round 1
// baseline (103.601 us; speedup 1.0000x reference)
//
#include <hip/hip_runtime.h>
#include <math.h>

#define DIM   64
#define HID   512
#define BATCH 8192

// d_ws layout (in floats)
#define W1T_OFF   0                       // [DIM][HID]  masked W1, transposed: W1T[i][j] = mask1[j][i]*W1[j][i]
#define W2M_OFF   (DIM * HID)             // [2*DIM][HID] masked W2
#define W2SUM_OFF (W2M_OFF + 2 * DIM * HID) // [HID] column sums of rows DIM..2*DIM-1 of W2M
#define B2SUM_OFF (W2SUM_OFF + HID)       // scalar: sum b2[DIM..2*DIM-1]
#define WS_FLOATS (B2SUM_OFF + 1)

__global__ void prep_kernel(const float* __restrict__ W1,
                            const float* __restrict__ mask1,
                            const float* __restrict__ W2,
                            const float* __restrict__ mask2,
                            const float* __restrict__ b2,
                            float* __restrict__ ws) {
    int t = blockIdx.x * blockDim.x + threadIdx.x;
    const int n1 = DIM * HID;       // 32768
    const int n2 = 2 * DIM * HID;   // 65536
    if (t < n1) {
        int i = t / HID;            // dim index
        int j = t - i * HID;        // hid index
        ws[W1T_OFF + t] = mask1[j * DIM + i] * W1[j * DIM + i];
    } else if (t < n1 + n2) {
        int u = t - n1;
        ws[W2M_OFF + u] = mask2[u] * W2[u];
    } else if (t < n1 + n2 + HID) {
        int j = t - n1 - n2;
        float s = 0.f;
        for (int r = 0; r < DIM; ++r) {
            int idx = (DIM + r) * HID + j;
            s += mask2[idx] * W2[idx];
        }
        ws[W2SUM_OFF + j] = s;
    } else if (t == n1 + n2 + HID) {
        float s = 0.f;
        for (int r = 0; r < DIM; ++r) s += b2[DIM + r];
        ws[B2SUM_OFF] = s;
    }
}

// one 64-lane wave per batch row; lane L holds h[8] = pre-activations 8L..8L+7
__global__ __launch_bounds__(256, 8) void maf_kernel(
    const float* __restrict__ z,
    const float* __restrict__ b1,
    const float* __restrict__ b2,
    const float* __restrict__ ws,
    float* __restrict__ out) {
    const int tid  = blockIdx.x * blockDim.x + threadIdx.x;
    const int b    = tid >> 6;
    const int lane = threadIdx.x & 63;
    if (b >= BATCH) return;

    const float* __restrict__ W1T   = ws + W1T_OFF;
    const float* __restrict__ W2M   = ws + W2M_OFF;
    const float* __restrict__ w2sum = ws + W2SUM_OFF;

    // persistent per-lane state
    float h[8];
#pragma unroll
    for (int k = 0; k < 8; ++k) h[k] = b1[lane * 8 + k];

    const float zl = z[b * DIM + lane];   // lane i holds z[b][i]
    float x_mine = 0.f;                   // lane i will end up holding x[b][i]

#pragma unroll 1
    for (int i = 0; i < DIM; ++i) {
        // relu of current pre-activations
        float rh[8];
#pragma unroll
        for (int k = 0; k < 8; ++k) rh[k] = fmaxf(h[k], 0.f);

        // two columns of layer-2 output: rows i (mu) and DIM+i (alpha) of W2M
        const float4* wmu = (const float4*)(W2M + i * HID + lane * 8);
        const float4* wal = (const float4*)(W2M + (DIM + i) * HID + lane * 8);
        float4 m0 = wmu[0], m1 = wmu[1];
        float4 a0 = wal[0], a1 = wal[1];

        float pm = rh[0] * m0.x + rh[1] * m0.y + rh[2] * m0.z + rh[3] * m0.w
                 + rh[4] * m1.x + rh[5] * m1.y + rh[6] * m1.z + rh[7] * m1.w;
        float pa = rh[0] * a0.x + rh[1] * a0.y + rh[2] * a0.z + rh[3] * a0.w
                 + rh[4] * a1.x + rh[5] * a1.y + rh[6] * a1.z + rh[7] * a1.w;

        // 64-lane butterfly sum (result broadcast to all lanes)
#pragma unroll
        for (int off = 32; off > 0; off >>= 1) {
            pm += __shfl_xor(pm, off, 64);
            pa += __shfl_xor(pa, off, 64);
        }

        const float mu = pm + b2[i];
        const float al = pa + b2[DIM + i];
        const float xi = __int_as_float(
            __builtin_amdgcn_readlane(__float_as_int(zl), i)); // z[b][i], uniform
        const float xv = xi * __expf(al) + mu;

        if (lane == i) x_mine = xv;

        // rank-1 update: h += xv * W1T[i][:]
        const float4* w1c = (const float4*)(W1T + i * HID + lane * 8);
        float4 c0 = w1c[0], c1 = w1c[1];
        h[0] += xv * c0.x; h[1] += xv * c0.y; h[2] += xv * c0.z; h[3] += xv * c0.w;
        h[4] += xv * c1.x; h[5] += xv * c1.y; h[6] += xv * c1.z; h[7] += xv * c1.w;
    }

    // x output (row of 64, coalesced per wave)
    out[b * DIM + lane] = x_mine;

    // log-det: relu(h_final) . w2sum + sum(b2[DIM:])
    const float4* s4 = (const float4*)(w2sum + lane * 8);
    float4 s0 = s4[0], s1 = s4[1];
    float pl = fmaxf(h[0], 0.f) * s0.x + fmaxf(h[1], 0.f) * s0.y
             + fmaxf(h[2], 0.f) * s0.z + fmaxf(h[3], 0.f) * s0.w
             + fmaxf(h[4], 0.f) * s1.x + fmaxf(h[5], 0.f) * s1.y
             + fmaxf(h[6], 0.f) * s1.z + fmaxf(h[7], 0.f) * s1.w;
#pragma unroll
    for (int off = 32; off > 0; off >>= 1) pl += __shfl_xor(pl, off, 64);

    if (lane == 0) out[BATCH * DIM + b] = pl + ws[B2SUM_OFF];
}

extern "C" void kernel_launch(void* const* d_in, const int* in_sizes, int n_in,
                              void* d_out, int out_size, void* d_ws, size_t ws_size,
                              hipStream_t stream) {
    const float* z     = (const float*)d_in[0];
    const float* W1    = (const float*)d_in[1];
    const float* b1    = (const float*)d_in[2];
    const float* W2    = (const float*)d_in[3];
    const float* b2    = (const float*)d_in[4];
    const float* mask1 = (const float*)d_in[5];
    const float* mask2 = (const float*)d_in[6];
    float* out = (float*)d_out;
    float* ws  = (float*)d_ws;

    // 1) build masked/transposed weights + logdet folding vectors in ws (~396 KB)
    {
        int total  = WS_FLOATS;
        int blocks = (total + 255) / 256;
        prep_kernel<<<blocks, 256, 0, stream>>>(W1, mask1, W2, mask2, b2, ws);
    }
    // 2) autoregressive scan: one wave per batch row
    {
        int threads = 256;                       // 4 waves/block
        int blocks  = (BATCH * 64) / threads;    // 2048 blocks
        maf_kernel<<<blocks, threads, 0, stream>>>(z, b1, b2, ws, out);
    }
}

// Round 4
// 99.720 us; speedup vs baseline: 1.0389x; 1.0389x over previous
//
#include <hip/hip_runtime.h>
#include <math.h>

#define DIM   64
#define HID   512
#define BATCH 8192

// d_ws layout (in floats)
#define W1T_OFF   0                         // [DIM][HID]  masked W1, transposed
#define W2M_OFF   (DIM * HID)               // [2*DIM][HID] masked W2
#define W2SUM_OFF (W2M_OFF + 2 * DIM * HID) // [HID] col sums of rows DIM..2*DIM-1
#define B2SUM_OFF (W2SUM_OFF + HID)         // scalar: sum b2[DIM..2*DIM-1]
#define WS_FLOATS (B2SUM_OFF + 1)

__global__ void prep_kernel(const float* __restrict__ W1,
                            const float* __restrict__ mask1,
                            const float* __restrict__ W2,
                            const float* __restrict__ mask2,
                            const float* __restrict__ b2,
                            float* __restrict__ ws) {
    int t = blockIdx.x * blockDim.x + threadIdx.x;
    const int n1 = DIM * HID;       // 32768
    const int n2 = 2 * DIM * HID;   // 65536
    if (t < n1) {
        int i = t / HID;
        int j = t - i * HID;
        ws[W1T_OFF + t] = mask1[j * DIM + i] * W1[j * DIM + i];
    } else if (t < n1 + n2) {
        int u = t - n1;
        ws[W2M_OFF + u] = mask2[u] * W2[u];
    } else if (t < n1 + n2 + HID) {
        int j = t - n1 - n2;
        float s = 0.f;
        for (int r = 0; r < DIM; ++r) {
            int idx = (DIM + r) * HID + j;
            s += mask2[idx] * W2[idx];
        }
        ws[W2SUM_OFF + j] = s;
    } else if (t == n1 + n2 + HID) {
        float s = 0.f;
        for (int r = 0; r < DIM; ++r) s += b2[DIM + r];
        ws[B2SUM_OFF] = s;
    }
}

// Full-wave (64-lane) sum via DPP, VALU-only. Result valid in lane 63.
__device__ __forceinline__ float wave_sum_dpp(float x) {
    // row_shr:1
    x += __int_as_float(__builtin_amdgcn_update_dpp(0, __float_as_int(x), 0x111, 0xf, 0xf, true));
    // row_shr:2
    x += __int_as_float(__builtin_amdgcn_update_dpp(0, __float_as_int(x), 0x112, 0xf, 0xf, true));
    // row_shr:4
    x += __int_as_float(__builtin_amdgcn_update_dpp(0, __float_as_int(x), 0x114, 0xf, 0xf, true));
    // row_shr:8  -> lane15 of each row-of-16 holds its row sum
    x += __int_as_float(__builtin_amdgcn_update_dpp(0, __float_as_int(x), 0x118, 0xf, 0xf, true));
    // row_bcast:15 (update rows 1,3) -> lane31 = sum lanes0-31, lane63 = sum lanes32-63
    x += __int_as_float(__builtin_amdgcn_update_dpp(0, __float_as_int(x), 0x142, 0xa, 0xf, true));
    // row_bcast:31 (update rows 2,3) -> lane63 = full 64-lane sum
    x += __int_as_float(__builtin_amdgcn_update_dpp(0, __float_as_int(x), 0x143, 0xc, 0xf, true));
    return x;
}

__device__ __forceinline__ float readlane_f(float v, int lane) {
    return __int_as_float(__builtin_amdgcn_readlane(__float_as_int(v), lane));
}

// one 64-lane wave per batch row; lane L holds h[8] = pre-activations 8L..8L+7
__global__ __launch_bounds__(256, 8) void maf_kernel(
    const float* __restrict__ z,
    const float* __restrict__ b1,
    const float* __restrict__ b2,
    const float* __restrict__ ws,
    float* __restrict__ out) {
    const int tid  = blockIdx.x * blockDim.x + threadIdx.x;
    const int b    = tid >> 6;
    const int lane = threadIdx.x & 63;
    if (b >= BATCH) return;

    const float* __restrict__ W1T   = ws + W1T_OFF;
    const float* __restrict__ W2M   = ws + W2M_OFF;
    const float* __restrict__ w2sum = ws + W2SUM_OFF;

    // persistent per-lane state
    float h[8];
#pragma unroll
    for (int k = 0; k < 8; ++k) h[k] = b1[lane * 8 + k];

    const float zl   = z[b * DIM + lane];  // lane i holds z[b][i]
    const float b2lo = b2[lane];           // lane i holds b2[i]
    const float b2hi = b2[DIM + lane];     // lane i holds b2[64+i]
    float x_mine = 0.f;

#pragma unroll 1
    for (int i = 0; i < DIM; ++i) {
        float rh[8];
#pragma unroll
        for (int k = 0; k < 8; ++k) rh[k] = fmaxf(h[k], 0.f);

        // two rows of masked W2: row i (mu) and row DIM+i (alpha)
        const float4* wmu = (const float4*)(W2M + i * HID + lane * 8);
        const float4* wal = (const float4*)(W2M + (DIM + i) * HID + lane * 8);
        float4 m0 = wmu[0], m1 = wmu[1];
        float4 a0 = wal[0], a1 = wal[1];

        float pm = rh[0] * m0.x + rh[1] * m0.y + rh[2] * m0.z + rh[3] * m0.w
                 + rh[4] * m1.x + rh[5] * m1.y + rh[6] * m1.z + rh[7] * m1.w;
        float pa = rh[0] * a0.x + rh[1] * a0.y + rh[2] * a0.z + rh[3] * a0.w
                 + rh[4] * a1.x + rh[5] * a1.y + rh[6] * a1.z + rh[7] * a1.w;

        // VALU-only full-wave reductions (two independent DPP chains)
        pm = wave_sum_dpp(pm);
        pa = wave_sum_dpp(pa);

        const float mu = readlane_f(pm, 63) + readlane_f(b2lo, i);
        const float al = readlane_f(pa, 63) + readlane_f(b2hi, i);
        const float xi = readlane_f(zl, i);
        const float xv = xi * __expf(al) + mu;   // wave-uniform

        if (lane == i) x_mine = xv;

        // rank-1 update: h += xv * W1T[i][:]
        const float4* w1c = (const float4*)(W1T + i * HID + lane * 8);
        float4 c0 = w1c[0], c1 = w1c[1];
        h[0] += xv * c0.x; h[1] += xv * c0.y; h[2] += xv * c0.z; h[3] += xv * c0.w;
        h[4] += xv * c1.x; h[5] += xv * c1.y; h[6] += xv * c1.z; h[7] += xv * c1.w;
    }

    // x output (row of 64, coalesced per wave)
    out[b * DIM + lane] = x_mine;

    // log-det: relu(h_final) . w2sum + sum(b2[DIM:])
    const float4* s4 = (const float4*)(w2sum + lane * 8);
    float4 s0 = s4[0], s1 = s4[1];
    float pl = fmaxf(h[0], 0.f) * s0.x + fmaxf(h[1], 0.f) * s0.y
             + fmaxf(h[2], 0.f) * s0.z + fmaxf(h[3], 0.f) * s0.w
             + fmaxf(h[4], 0.f) * s1.x + fmaxf(h[5], 0.f) * s1.y
             + fmaxf(h[6], 0.f) * s1.z + fmaxf(h[7], 0.f) * s1.w;
    pl = wave_sum_dpp(pl);
    if (lane == 63) out[BATCH * DIM + b] = pl + ws[B2SUM_OFF];
}

extern "C" void kernel_launch(void* const* d_in, const int* in_sizes, int n_in,
                              void* d_out, int out_size, void* d_ws, size_t ws_size,
                              hipStream_t stream) {
    const float* z     = (const float*)d_in[0];
    const float* W1    = (const float*)d_in[1];
    const float* b1    = (const float*)d_in[2];
    const float* W2    = (const float*)d_in[3];
    const float* b2    = (const float*)d_in[4];
    const float* mask1 = (const float*)d_in[5];
    const float* mask2 = (const float*)d_in[6];
    float* out = (float*)d_out;
    float* ws  = (float*)d_ws;

    {
        int total  = WS_FLOATS;
        int blocks = (total + 255) / 256;
        prep_kernel<<<blocks, 256, 0, stream>>>(W1, mask1, W2, mask2, b2, ws);
    }
    {
        int threads = 256;                    // 4 waves/block
        int blocks  = (BATCH * 64) / threads; // 2048 blocks
        maf_kernel<<<blocks, threads, 0, stream>>>(z, b1, b2, ws, out);
    }
}

// Round 8
// 73.382 us; speedup vs baseline: 1.4118x; 1.3589x over previous
//
#include <hip/hip_runtime.h>
#include <math.h>

#define DIM   64
#define HID   512
#define BATCH 8192
#define R     4     // batch rows per wave

// d_ws layout (in floats)
#define W1T_OFF   0                         // [DIM][HID]  masked W1, transposed
#define W2M_OFF   (DIM * HID)               // [2*DIM][HID] masked W2
#define W2SUM_OFF (W2M_OFF + 2 * DIM * HID) // [HID] col sums of rows DIM..2*DIM-1
#define B2SUM_OFF (W2SUM_OFF + HID)         // scalar: sum b2[DIM..2*DIM-1]
#define WS_FLOATS (B2SUM_OFF + 1)

__global__ void prep_kernel(const float* __restrict__ W1,
                            const float* __restrict__ mask1,
                            const float* __restrict__ W2,
                            const float* __restrict__ mask2,
                            const float* __restrict__ b2,
                            float* __restrict__ ws) {
    int t = blockIdx.x * blockDim.x + threadIdx.x;
    const int n1 = DIM * HID;       // 32768
    const int n2 = 2 * DIM * HID;   // 65536
    if (t < n1) {
        int i = t / HID;
        int j = t - i * HID;
        ws[W1T_OFF + t] = mask1[j * DIM + i] * W1[j * DIM + i];
    } else if (t < n1 + n2) {
        int u = t - n1;
        ws[W2M_OFF + u] = mask2[u] * W2[u];
    } else if (t < n1 + n2 + HID) {
        int j = t - n1 - n2;
        float s = 0.f;
        for (int r = 0; r < DIM; ++r) {
            int idx = (DIM + r) * HID + j;
            s += mask2[idx] * W2[idx];
        }
        ws[W2SUM_OFF + j] = s;
    } else if (t == n1 + n2 + HID) {
        float s = 0.f;
        for (int r = 0; r < DIM; ++r) s += b2[DIM + r];
        ws[B2SUM_OFF] = s;
    }
}

// Full-wave (64-lane) sum via DPP, VALU-only. Result valid in lane 63.
__device__ __forceinline__ float wave_sum_dpp(float x) {
    x += __int_as_float(__builtin_amdgcn_update_dpp(0, __float_as_int(x), 0x111, 0xf, 0xf, true)); // row_shr:1
    x += __int_as_float(__builtin_amdgcn_update_dpp(0, __float_as_int(x), 0x112, 0xf, 0xf, true)); // row_shr:2
    x += __int_as_float(__builtin_amdgcn_update_dpp(0, __float_as_int(x), 0x114, 0xf, 0xf, true)); // row_shr:4
    x += __int_as_float(__builtin_amdgcn_update_dpp(0, __float_as_int(x), 0x118, 0xf, 0xf, true)); // row_shr:8
    x += __int_as_float(__builtin_amdgcn_update_dpp(0, __float_as_int(x), 0x142, 0xa, 0xf, true)); // row_bcast:15
    x += __int_as_float(__builtin_amdgcn_update_dpp(0, __float_as_int(x), 0x143, 0xc, 0xf, true)); // row_bcast:31
    return x;
}

__device__ __forceinline__ float readlane_f(float v, int lane) {
    return __int_as_float(__builtin_amdgcn_readlane(__float_as_int(v), lane));
}

// one 64-lane wave per R batch rows; lane L holds h[r][8] = pre-activations 8L..8L+7
__global__ __launch_bounds__(256, 2) void maf_kernel(
    const float* __restrict__ z,
    const float* __restrict__ b1,
    const float* __restrict__ b2,
    const float* __restrict__ ws,
    float* __restrict__ out) {
    const int lane = threadIdx.x & 63;
    const int wid  = (blockIdx.x * blockDim.x + threadIdx.x) >> 6;
    const int b0   = wid * R;

    const float* __restrict__ W1T = ws + W1T_OFF;
    const float* __restrict__ W2M = ws + W2M_OFF;
    const float* __restrict__ w2s = ws + W2SUM_OFF;

    // persistent per-lane state: h for R rows
    float h[R][8];
    {
        const float4* bp = (const float4*)(b1 + lane * 8);
        float4 bv0 = bp[0], bv1 = bp[1];
#pragma unroll
        for (int r = 0; r < R; ++r) {
            h[r][0] = bv0.x; h[r][1] = bv0.y; h[r][2] = bv0.z; h[r][3] = bv0.w;
            h[r][4] = bv1.x; h[r][5] = bv1.y; h[r][6] = bv1.z; h[r][7] = bv1.w;
        }
    }
    float zl[R];
#pragma unroll
    for (int r = 0; r < R; ++r) zl[r] = z[(b0 + r) * DIM + lane];
    const float b2lo = b2[lane];
    const float b2hi = b2[DIM + lane];
    float xm[R] = {0.f, 0.f, 0.f, 0.f};

#define LOADW(i, m0, m1, a0, a1, c0, c1)                                   \
    do {                                                                   \
        const float4* _pm = (const float4*)(W2M + (i) * HID + lane * 8);   \
        const float4* _pa = (const float4*)(W2M + ((i) + DIM) * HID + lane * 8); \
        const float4* _pc = (const float4*)(W1T + (i) * HID + lane * 8);   \
        m0 = _pm[0]; m1 = _pm[1];                                          \
        a0 = _pa[0]; a1 = _pa[1];                                          \
        c0 = _pc[0]; c1 = _pc[1];                                          \
    } while (0)

#define STEP(i, m0, m1, a0, a1, c0, c1)                                    \
    do {                                                                   \
        float _pmv[R], _pav[R];                                            \
        _Pragma("unroll")                                                  \
        for (int r = 0; r < R; ++r) {                                      \
            float rh0 = fmaxf(h[r][0], 0.f), rh1 = fmaxf(h[r][1], 0.f);    \
            float rh2 = fmaxf(h[r][2], 0.f), rh3 = fmaxf(h[r][3], 0.f);    \
            float rh4 = fmaxf(h[r][4], 0.f), rh5 = fmaxf(h[r][5], 0.f);    \
            float rh6 = fmaxf(h[r][6], 0.f), rh7 = fmaxf(h[r][7], 0.f);    \
            float pm = rh0 * m0.x + rh1 * m0.y + rh2 * m0.z + rh3 * m0.w   \
                     + rh4 * m1.x + rh5 * m1.y + rh6 * m1.z + rh7 * m1.w;  \
            float pa = rh0 * a0.x + rh1 * a0.y + rh2 * a0.z + rh3 * a0.w   \
                     + rh4 * a1.x + rh5 * a1.y + rh6 * a1.z + rh7 * a1.w;  \
            _pmv[r] = wave_sum_dpp(pm);                                    \
            _pav[r] = wave_sum_dpp(pa);                                    \
        }                                                                  \
        const float _b2i  = readlane_f(b2lo, (i));                         \
        const float _b2di = readlane_f(b2hi, (i));                         \
        _Pragma("unroll")                                                  \
        for (int r = 0; r < R; ++r) {                                      \
            const float _zi = readlane_f(zl[r], (i));                      \
            float _xv = _zi * __expf(_pav[r] + _b2di) + (_pmv[r] + _b2i);  \
            const float _xs = readlane_f(_xv, 63);                         \
            if (lane == (i)) xm[r] = _xs;                                  \
            h[r][0] += _xs * c0.x; h[r][1] += _xs * c0.y;                  \
            h[r][2] += _xs * c0.z; h[r][3] += _xs * c0.w;                  \
            h[r][4] += _xs * c1.x; h[r][5] += _xs * c1.y;                  \
            h[r][6] += _xs * c1.z; h[r][7] += _xs * c1.w;                  \
        }                                                                  \
    } while (0)

    // double-buffered weight registers, 1-step-ahead prefetch
    float4 m0A, m1A, a0A, a1A, c0A, c1A;
    float4 m0B, m1B, a0B, a1B, c0B, c1B;
    LOADW(0, m0A, m1A, a0A, a1A, c0A, c1A);

#pragma unroll 1
    for (int i = 0; i < DIM; i += 2) {
        LOADW(i + 1, m0B, m1B, a0B, a1B, c0B, c1B);
        __builtin_amdgcn_s_barrier();   // keep block's 4 waves time-aligned for L1 reuse
        STEP(i, m0A, m1A, a0A, a1A, c0A, c1A);
        LOADW((i + 2) & 63, m0A, m1A, a0A, a1A, c0A, c1A);
        STEP(i + 1, m0B, m1B, a0B, a1B, c0B, c1B);
    }

    // epilogue: x writes + log-det
    const float4* sp = (const float4*)(w2s + lane * 8);
    float4 s0 = sp[0], s1 = sp[1];
    const float bsum = ws[B2SUM_OFF];
#pragma unroll
    for (int r = 0; r < R; ++r) {
        out[(b0 + r) * DIM + lane] = xm[r];
        float pl = fmaxf(h[r][0], 0.f) * s0.x + fmaxf(h[r][1], 0.f) * s0.y
                 + fmaxf(h[r][2], 0.f) * s0.z + fmaxf(h[r][3], 0.f) * s0.w
                 + fmaxf(h[r][4], 0.f) * s1.x + fmaxf(h[r][5], 0.f) * s1.y
                 + fmaxf(h[r][6], 0.f) * s1.z + fmaxf(h[r][7], 0.f) * s1.w;
        pl = wave_sum_dpp(pl);
        if (lane == 63) out[BATCH * DIM + b0 + r] = pl + bsum;
    }
#undef LOADW
#undef STEP
}

extern "C" void kernel_launch(void* const* d_in, const int* in_sizes, int n_in,
                              void* d_out, int out_size, void* d_ws, size_t ws_size,
                              hipStream_t stream) {
    const float* z     = (const float*)d_in[0];
    const float* W1    = (const float*)d_in[1];
    const float* b1    = (const float*)d_in[2];
    const float* W2    = (const float*)d_in[3];
    const float* b2    = (const float*)d_in[4];
    const float* mask1 = (const float*)d_in[5];
    const float* mask2 = (const float*)d_in[6];
    float* out = (float*)d_out;
    float* ws  = (float*)d_ws;

    {
        int total  = WS_FLOATS;
        int blocks = (total + 255) / 256;
        prep_kernel<<<blocks, 256, 0, stream>>>(W1, mask1, W2, mask2, b2, ws);
    }
    {
        int threads = 256;                        // 4 waves/block, R rows each
        int blocks  = BATCH / (R * 4);            // 512 blocks
        maf_kernel<<<blocks, threads, 0, stream>>>(z, b1, b2, ws, out);
    }
}